// Round 1
// 454.341 us; speedup vs baseline: 1.1749x; 1.1749x over previous
//
#include <hip/hip_runtime.h>
#include <stdint.h>

typedef unsigned short u16;
typedef u16      u16x8 __attribute__((ext_vector_type(8)));
typedef _Float16 f16x8 __attribute__((ext_vector_type(8)));
typedef float    f32x4 __attribute__((ext_vector_type(4)));

#define HIDDEN 128   // NH(8) * HD(16)

// INPUTS fp32, OUTPUT fp32 (proven). W/Q/K/V stored fp16 (absmax 0.031 vs
// 0.105 threshold), all accumulation fp32.
//
// Round change: attn restructured for memory-level parallelism.
//  - K and V interleaved per node: 32 x uint4; entry j = {K[4j..4j+3], V[4j..4j+3]}
//    -> one global_load_dwordx4 per lane fetches both K and V fragments.
//  - Half-wave split: lanes 0..31 process even edges, 32..63 odd edges (two
//    independent online-softmax states, merged via shfl_xor(32) at the end).
//  - Cooperative srcperm preload (64 indices per vector load).
//  - 2-deep software pipeline: >= 2 x 512B gathers in flight per wave.
//  - Head reduce (16 dims = 4 lanes) via DPP quad_perm instead of ds_swizzle.

__device__ __forceinline__ float h2f(u16 u) {
    _Float16 h; __builtin_memcpy(&h, &u, 2); return (float)h;
}
__device__ __forceinline__ u16 f2h(float f) {
    _Float16 h = (_Float16)f; u16 u; __builtin_memcpy(&u, &h, 2); return u;
}
__device__ __forceinline__ float lo16f(uint32_t u) { return h2f((u16)(u & 0xffff)); }
__device__ __forceinline__ float hi16f(uint32_t u) { return h2f((u16)(u >> 16)); }

// quad_perm DPP cross-lane: CTRL=0xB1 -> lane^1, CTRL=0x4E -> lane^2
template <int CTRL>
__device__ __forceinline__ float dpp_qperm(float x) {
#if __has_builtin(__builtin_amdgcn_update_dpp)
    int r = __builtin_amdgcn_update_dpp(0, __builtin_bit_cast(int, x), CTRL, 0xF, 0xF, true);
    return __builtin_bit_cast(float, r);
#else
    return __shfl_xor(x, (CTRL == 0xB1) ? 1 : 2);
#endif
}

// ---------------------------------------------------------------------------
// Pack [Wq|Wk|Wv] (128x128 row-major fp32 W[k][c]) into fp16 MFMA B-fragment
// order for mfma_f32_16x16x32_f16: lane l elem j holds
// B[k = kt*32 + (l>>4)*8 + j][c = (ct&7)*16 + (l&15)], ct = w*8 + col_tile.
// ---------------------------------------------------------------------------
__global__ void pack_w_kernel(const float* __restrict__ Wq, const float* __restrict__ Wk,
                              const float* __restrict__ Wv, u16* __restrict__ packed) {
    int tid = blockIdx.x * blockDim.x + threadIdx.x;
    if (tid >= 24 * 4 * 64 * 8) return;
    int j    = tid & 7;
    int lane = (tid >> 3) & 63;
    int kt   = (tid >> 9) & 3;
    int ct   = tid >> 11;            // 0..23
    int w    = ct >> 3;
    int k    = kt * 32 + ((lane >> 4) << 3) + j;
    int c    = (ct & 7) * 16 + (lane & 15);
    const float* W = (w == 0) ? Wq : (w == 1) ? Wk : Wv;
    packed[tid] = f2h(W[k * HIDDEN + c]);
}

// ---------------------------------------------------------------------------
// MFMA QKV projection (HW-verified fragment mappings). Block 256 = 4 waves;
// wave: 16 rows x 384 cols. Q written row-major fp16; K/V written into the
// interleaved KV layout consumed by attn:
//   u16 index = node*256 + (cc>>2)*8 + (isV ? 4 : 0) + (cc&3)
// ---------------------------------------------------------------------------
__global__ __launch_bounds__(256) void qkv_gemm_mfma(
    const float* __restrict__ h, const u16* __restrict__ packed,
    const float* __restrict__ bq, const float* __restrict__ bk, const float* __restrict__ bv,
    u16* __restrict__ Qb, u16* __restrict__ KVb, int n) {
    int wave = threadIdx.x >> 6, lane = threadIdx.x & 63;
    int row0 = blockIdx.x * 64 + wave * 16;
    int m = lane & 15, quad = lane >> 4;
    int arow = row0 + m;

    u16x8 a[4];
    if (arow < n) {
        const float* hp = h + (size_t)arow * HIDDEN + quad * 8;
        #pragma unroll
        for (int kt = 0; kt < 4; ++kt) {
            f32x4 lo = *(const f32x4*)(hp + kt * 32);
            f32x4 hi = *(const f32x4*)(hp + kt * 32 + 4);
            #pragma unroll
            for (int j = 0; j < 4; ++j) {
                a[kt][j]     = f2h(lo[j]);
                a[kt][j + 4] = f2h(hi[j]);
            }
        }
    } else {
        #pragma unroll
        for (int kt = 0; kt < 4; ++kt) a[kt] = (u16x8){0,0,0,0,0,0,0,0};
    }

    #pragma unroll
    for (int ct = 0; ct < 24; ++ct) {
        f32x4 acc = {0.f, 0.f, 0.f, 0.f};
        #pragma unroll
        for (int kt = 0; kt < 4; ++kt) {
            u16x8 b = *(const u16x8*)(packed + (((ct * 4 + kt) * 64 + lane) << 3));
            acc = __builtin_amdgcn_mfma_f32_16x16x32_f16(
                __builtin_bit_cast(f16x8, a[kt]), __builtin_bit_cast(f16x8, b),
                acc, 0, 0, 0);
        }
        int w  = ct >> 3;                 // compile-time after unroll
        int cc = (ct & 7) * 16 + m;
        const float* bp = (w == 0) ? bq : (w == 1) ? bk : bv;
        float bias = bp[cc];
        #pragma unroll
        for (int r = 0; r < 4; ++r) {
            int rr = row0 + quad * 4 + r;
            if (rr < n) {
                u16 val = f2h(acc[r] + bias);
                if (w == 0) {
                    Qb[(size_t)rr * HIDDEN + cc] = val;
                } else {
                    KVb[(size_t)rr * 256 + ((cc >> 2) << 3) + ((w == 2) ? 4 : 0) + (cc & 3)] = val;
                }
            }
        }
    }
}

// ---------------------------------------------------------------------------
// CSR build: histogram, parallel 2-level scan, scatter (post-increments
// offsets; attn recovers start = offsets[d] - counts[d]).
// ---------------------------------------------------------------------------
__global__ void count_kernel(const int* __restrict__ dst, int* __restrict__ counts, int e) {
    int i = blockIdx.x * blockDim.x + threadIdx.x;
    if (i < e) atomicAdd(&counts[dst[i]], 1);
}

// Phase 1: per-block sums (block = 256 thr x 4 items = 1024 elements).
__global__ __launch_bounds__(256) void scan_partial(const int* __restrict__ counts,
                                                    int* __restrict__ blockSums, int n) {
    __shared__ int red[256];
    int t = threadIdx.x;
    int base = blockIdx.x * 1024 + t * 4;
    int s = 0;
    #pragma unroll
    for (int j = 0; j < 4; ++j) { int i = base + j; if (i < n) s += counts[i]; }
    red[t] = s;
    __syncthreads();
    #pragma unroll
    for (int off = 128; off > 0; off >>= 1) {
        if (t < off) red[t] += red[t + off];
        __syncthreads();
    }
    if (t == 0) blockSums[blockIdx.x] = red[0];
}

// Phase 2: exclusive scan of block sums (nb <= 256) + grand total -> offsets[n].
__global__ __launch_bounds__(256) void scan_blocksums(int* __restrict__ blockSums,
                                                      int* __restrict__ offsets,
                                                      int nb, int n) {
    __shared__ int buf[256];
    int t = threadIdx.x;
    int v = (t < nb) ? blockSums[t] : 0;
    buf[t] = v;
    __syncthreads();
    #pragma unroll
    for (int off = 1; off < 256; off <<= 1) {
        int x = (t >= off) ? buf[t - off] : 0;
        __syncthreads();
        buf[t] += x;
        __syncthreads();
    }
    if (t < nb) blockSums[t] = buf[t] - v;     // exclusive base for block t
    if (t == 255) offsets[n] = buf[255];       // grand total
}

// Phase 3: per-block re-scan with base.
__global__ __launch_bounds__(256) void scan_final(const int* __restrict__ counts,
                                                  const int* __restrict__ blockSums,
                                                  int* __restrict__ offsets, int n) {
    __shared__ int buf[256];
    int t = threadIdx.x;
    int base = blockIdx.x * 1024 + t * 4;
    int c[4];
    #pragma unroll
    for (int j = 0; j < 4; ++j) { int i = base + j; c[j] = (i < n) ? counts[i] : 0; }
    int tsum = c[0] + c[1] + c[2] + c[3];
    buf[t] = tsum;
    __syncthreads();
    #pragma unroll
    for (int off = 1; off < 256; off <<= 1) {
        int x = (t >= off) ? buf[t - off] : 0;
        __syncthreads();
        buf[t] += x;
        __syncthreads();
    }
    int run = blockSums[blockIdx.x] + buf[t] - tsum;
    #pragma unroll
    for (int j = 0; j < 4; ++j) {
        int i = base + j;
        if (i < n) { offsets[i] = run; run += c[j]; }
    }
}

__global__ void scatter_kernel(const int* __restrict__ src, const int* __restrict__ dst,
                               int* __restrict__ offsets, int* __restrict__ srcperm, int e) {
    int i = blockIdx.x * blockDim.x + threadIdx.x;
    if (i < e) {
        int p = atomicAdd(&offsets[dst[i]], 1);
        if (p >= 0 && p < e) srcperm[p] = src[i];
    }
}

// ---------------------------------------------------------------------------
// One wave per dst node, split into two 32-lane halves processing even/odd
// edges with independent online-softmax states (merged at the end).
// Lane j (= lane&31) owns dims {4j..4j+3}; head (16 dims) = 4 lanes; score
// reduce via DPP quad_perm xor1/xor2. One dwordx4 per lane fetches the
// interleaved {K,V} fragment. 2-deep pipeline keeps >=2 gathers in flight.
// ---------------------------------------------------------------------------
__global__ __launch_bounds__(256) void attn_kernel(
    const u16* __restrict__ Qb, const uint4* __restrict__ KVb,
    const int* __restrict__ offsets, const int* __restrict__ counts,
    const int* __restrict__ srcperm, float* __restrict__ out, int n, int e) {
    int node = blockIdx.x * 4 + (threadIdx.x >> 6);
    int lane = threadIdx.x & 63;
    if (node >= n) return;
    int j = lane & 31;      // dim group: dims 4j..4j+3
    int h = lane >> 5;      // half: processes edges with (idx & 1) == h

    uint2 qp = *(const uint2*)(Qb + (size_t)node * HIDDEN + j * 4);
    float q0 = lo16f(qp.x), q1 = hi16f(qp.x);
    float q2 = lo16f(qp.y), q3 = hi16f(qp.y);

    int deg = counts[node];
    if (deg < 0) deg = 0; if (deg > e) deg = e;
    int off = offsets[node] - deg;                       // offsets was post-incremented
    if (off < 0) off = 0; if (off > e - deg) off = e - deg;

    // online softmax state (per half-wave); finite sentinel so padded edges
    // (pv = -1e30) are exact no-ops: mn=mrun, scale=exp(0)=1, w=0.
    float mrun = -1e30f, lrun = 0.f;
    float o0 = 0.f, o1 = 0.f, o2 = 0.f, o3 = 0.f;

    for (int base = 0; base < deg; base += 64) {
        int cnt = deg - base; if (cnt > 64) cnt = 64;
        // cooperative srcperm preload: 64 indices in one vector load
        int sv = 0;
        if (lane < cnt) {
            int s = srcperm[off + base + lane];
            if (s < 0) s = 0; if (s >= n) s = n - 1;
            sv = s;
        }
        // pipeline prologue: edges {h, 2+h} (indices past cnt read sv=0 -> safe)
        uint4 kvA = KVb[(size_t)__shfl(sv, h) * 32 + j];
        uint4 kvB = KVb[(size_t)__shfl(sv, 2 + h) * 32 + j];
        for (int i = 0; i < cnt; i += 2) {
            uint4 kv = kvA;
            kvA = kvB;
            int ip = i + 4 + h; if (ip > 63) ip = 63;   // clamped prefetch (safe dummy)
            kvB = KVb[(size_t)__shfl(sv, ip) * 32 + j];

            float p = q0 * lo16f(kv.x) + q1 * hi16f(kv.x)
                    + q2 * lo16f(kv.y) + q3 * hi16f(kv.y);
            p += dpp_qperm<0xB1>(p);                    // lane^1
            p += dpp_qperm<0x4E>(p);                    // lane^2 -> head sum in all 4
            bool valid = (i + h) < cnt;
            float pv = valid ? p : -1e30f;
            float mn  = fmaxf(mrun, pv);
            float scl = __expf(mrun - mn);
            float w   = valid ? __expf(pv - mn) : 0.f;
            lrun = lrun * scl + w;
            o0 = o0 * scl + w * lo16f(kv.z);
            o1 = o1 * scl + w * hi16f(kv.z);
            o2 = o2 * scl + w * lo16f(kv.w);
            o3 = o3 * scl + w * hi16f(kv.w);
            mrun = mn;
        }
    }

    // merge the two half-wave states
    float mo  = __shfl_xor(mrun, 32);
    float lo_ = __shfl_xor(lrun, 32);
    float p0 = __shfl_xor(o0, 32), p1 = __shfl_xor(o1, 32);
    float p2 = __shfl_xor(o2, 32), p3 = __shfl_xor(o3, 32);
    float m2 = fmaxf(mrun, mo);
    float sa = __expf(mrun - m2), sb = __expf(mo - m2);
    float l  = lrun * sa + lo_ * sb;
    float inv = (l > 0.f) ? 1.f / l : 0.f;
    if (h == 0) {
        float4 r;
        r.x = (o0 * sa + p0 * sb) * inv;
        r.y = (o1 * sa + p1 * sb) * inv;
        r.z = (o2 * sa + p2 * sb) * inv;
        r.w = (o3 * sa + p3 * sb) * inv;
        *(float4*)(out + (size_t)node * HIDDEN + j * 4) = r;
    }
}

// ---------------------------------------------------------------------------
extern "C" void kernel_launch(void* const* d_in, const int* in_sizes, int n_in,
                              void* d_out, int out_size, void* d_ws, size_t ws_size,
                              hipStream_t stream) {
    const float* h   = (const float*)d_in[0];
    const int*   src = (const int*)d_in[1];
    const int*   dst = (const int*)d_in[2];
    const float* Wq  = (const float*)d_in[3];
    const float* bq  = (const float*)d_in[4];
    const float* Wk  = (const float*)d_in[5];
    const float* bk  = (const float*)d_in[6];
    const float* Wv  = (const float*)d_in[7];
    const float* bv  = (const float*)d_in[8];
    float* out = (float*)d_out;

    const int n = in_sizes[0] / HIDDEN;   // 100000
    const int e = in_sizes[1];            // 1600000
    const int nbScan = (n + 1023) / 1024; // 98 (<= 256 required by scan_blocksums)

    // Workspace carve — total ~83.7 MB (ws_size >= 84.5 MB proven).
    char* ws = (char*)d_ws;
    auto align256 = [](size_t x) { return (x + 255) & ~(size_t)255; };
    int* counts    = (int*)ws; ws += align256((size_t)n * 4);
    int* offsets   = (int*)ws; ws += align256((size_t)(n + 1) * 4);
    int* blockSums = (int*)ws; ws += align256((size_t)256 * 4);
    int* srcperm   = (int*)ws; ws += align256((size_t)e * 4);
    u16* packed    = (u16*)ws; ws += align256((size_t)24 * 4 * 64 * 8 * sizeof(u16));
    u16* Qb        = (u16*)ws; ws += align256((size_t)n * HIDDEN * sizeof(u16));
    u16* KVb       = (u16*)ws; ws += align256((size_t)n * 256 * sizeof(u16));

    hipMemsetAsync(counts, 0, (size_t)n * 4, stream);

    pack_w_kernel<<<(24 * 4 * 64 * 8 + 255) / 256, 256, 0, stream>>>(Wq, Wk, Wv, packed);
    qkv_gemm_mfma<<<(n + 63) / 64, 256, 0, stream>>>(h, packed, bq, bk, bv, Qb, KVb, n);
    count_kernel<<<(e + 255) / 256, 256, 0, stream>>>(dst, counts, e);
    scan_partial<<<nbScan, 256, 0, stream>>>(counts, blockSums, n);
    scan_blocksums<<<1, 256, 0, stream>>>(blockSums, offsets, nbScan, n);
    scan_final<<<nbScan, 256, 0, stream>>>(counts, blockSums, offsets, n);
    scatter_kernel<<<(e + 255) / 256, 256, 0, stream>>>(src, dst, offsets, srcperm, e);
    attn_kernel<<<(n + 3) / 4, 256, 0, stream>>>(Qb, (const uint4*)KVb, offsets, counts,
                                                 srcperm, out, n, e);
}

// Round 2
// 331.398 us; speedup vs baseline: 1.6108x; 1.3710x over previous
//
#include <hip/hip_runtime.h>
#include <stdint.h>

typedef unsigned short u16;
typedef u16      u16x8 __attribute__((ext_vector_type(8)));
typedef _Float16 f16x8 __attribute__((ext_vector_type(8)));
typedef float    f32x4 __attribute__((ext_vector_type(4)));
typedef unsigned long long u64;

#define HIDDEN 128   // NH(8) * HD(16)
#define BSH    9     // bucket shift: 512 nodes/bucket
#define NPB    (1 << BSH)
#define MAXBUK 256   // requires (n+NPB-1)>>BSH <= 256  (n=100000 -> 196)
#define PAD    16    // 64B stride for atomic counters (kill same-line serialization)

// INPUTS fp32, OUTPUT fp32. W/Q/K/V stored fp16 (absmax 0.031 vs 0.105
// threshold), all accumulation fp32.
//
// Round change: CSR build rewritten as a two-level counting sort.
//  - Old path (count 1.6M global atomics + 3 scans + scatter with 1.6M
//    atomic-with-return + random 4B stores -> 105MB HBM write amplification)
//    is deleted.
//  - New: bucket_hist (LDS hist, padded global counters) -> 256-wide scan ->
//    bucket_scatter (pairs written in ~256B per-bucket runs, L2 write-combined)
//    -> csr_finalize (per-bucket LDS hist/scan/rank, stores confined to a
//    32KB L2-hot window; emits compact starts[] so attn drops counts gather).
//  - pairs scratch (e*8B = 12.8MB) lives in d_out (51.2MB), consumed before
//    attn writes out.

__device__ __forceinline__ float h2f(u16 u) {
    _Float16 h; __builtin_memcpy(&h, &u, 2); return (float)h;
}
__device__ __forceinline__ u16 f2h(float f) {
    _Float16 h = (_Float16)f; u16 u; __builtin_memcpy(&u, &h, 2); return u;
}
__device__ __forceinline__ float lo16f(uint32_t u) { return h2f((u16)(u & 0xffff)); }
__device__ __forceinline__ float hi16f(uint32_t u) { return h2f((u16)(u >> 16)); }

// quad_perm DPP cross-lane: CTRL=0xB1 -> lane^1, CTRL=0x4E -> lane^2
template <int CTRL>
__device__ __forceinline__ float dpp_qperm(float x) {
#if __has_builtin(__builtin_amdgcn_update_dpp)
    int r = __builtin_amdgcn_update_dpp(0, __builtin_bit_cast(int, x), CTRL, 0xF, 0xF, true);
    return __builtin_bit_cast(float, r);
#else
    return __shfl_xor(x, (CTRL == 0xB1) ? 1 : 2);
#endif
}

// ---------------------------------------------------------------------------
// Pack [Wq|Wk|Wv] (128x128 row-major fp32 W[k][c]) into fp16 MFMA B-fragment
// order for mfma_f32_16x16x32_f16: lane l elem j holds
// B[k = kt*32 + (l>>4)*8 + j][c = (ct&7)*16 + (l&15)], ct = w*8 + col_tile.
// ---------------------------------------------------------------------------
__global__ void pack_w_kernel(const float* __restrict__ Wq, const float* __restrict__ Wk,
                              const float* __restrict__ Wv, u16* __restrict__ packed) {
    int tid = blockIdx.x * blockDim.x + threadIdx.x;
    if (tid >= 24 * 4 * 64 * 8) return;
    int j    = tid & 7;
    int lane = (tid >> 3) & 63;
    int kt   = (tid >> 9) & 3;
    int ct   = tid >> 11;            // 0..23
    int w    = ct >> 3;
    int k    = kt * 32 + ((lane >> 4) << 3) + j;
    int c    = (ct & 7) * 16 + (lane & 15);
    const float* W = (w == 0) ? Wq : (w == 1) ? Wk : Wv;
    packed[tid] = f2h(W[k * HIDDEN + c]);
}

// ---------------------------------------------------------------------------
// MFMA QKV projection. Block 256 = 4 waves; wave: 16 rows x 384 cols.
// Q row-major fp16; K/V interleaved for attn:
//   u16 index = node*256 + (cc>>2)*8 + (isV ? 4 : 0) + (cc&3)
// ---------------------------------------------------------------------------
__global__ __launch_bounds__(256) void qkv_gemm_mfma(
    const float* __restrict__ h, const u16* __restrict__ packed,
    const float* __restrict__ bq, const float* __restrict__ bk, const float* __restrict__ bv,
    u16* __restrict__ Qb, u16* __restrict__ KVb, int n) {
    int wave = threadIdx.x >> 6, lane = threadIdx.x & 63;
    int row0 = blockIdx.x * 64 + wave * 16;
    int m = lane & 15, quad = lane >> 4;
    int arow = row0 + m;

    u16x8 a[4];
    if (arow < n) {
        const float* hp = h + (size_t)arow * HIDDEN + quad * 8;
        #pragma unroll
        for (int kt = 0; kt < 4; ++kt) {
            f32x4 lo = *(const f32x4*)(hp + kt * 32);
            f32x4 hi = *(const f32x4*)(hp + kt * 32 + 4);
            #pragma unroll
            for (int j = 0; j < 4; ++j) {
                a[kt][j]     = f2h(lo[j]);
                a[kt][j + 4] = f2h(hi[j]);
            }
        }
    } else {
        #pragma unroll
        for (int kt = 0; kt < 4; ++kt) a[kt] = (u16x8){0,0,0,0,0,0,0,0};
    }

    #pragma unroll
    for (int ct = 0; ct < 24; ++ct) {
        f32x4 acc = {0.f, 0.f, 0.f, 0.f};
        #pragma unroll
        for (int kt = 0; kt < 4; ++kt) {
            u16x8 b = *(const u16x8*)(packed + (((ct * 4 + kt) * 64 + lane) << 3));
            acc = __builtin_amdgcn_mfma_f32_16x16x32_f16(
                __builtin_bit_cast(f16x8, a[kt]), __builtin_bit_cast(f16x8, b),
                acc, 0, 0, 0);
        }
        int w  = ct >> 3;                 // compile-time after unroll
        int cc = (ct & 7) * 16 + m;
        const float* bp = (w == 0) ? bq : (w == 1) ? bk : bv;
        float bias = bp[cc];
        #pragma unroll
        for (int r = 0; r < 4; ++r) {
            int rr = row0 + quad * 4 + r;
            if (rr < n) {
                u16 val = f2h(acc[r] + bias);
                if (w == 0) {
                    Qb[(size_t)rr * HIDDEN + cc] = val;
                } else {
                    KVb[(size_t)rr * 256 + ((cc >> 2) << 3) + ((w == 2) ? 4 : 0) + (cc & 3)] = val;
                }
            }
        }
    }
}

// ---------------------------------------------------------------------------
// CSR build, two-level counting sort.
// ---------------------------------------------------------------------------
// Phase 1: bucket histogram. LDS hist + one padded global atomic per
// (block,bucket): per-counter serialization = nblocks (256), each counter on
// its own 64B line.
__global__ __launch_bounds__(256) void bucket_hist(const int* __restrict__ dst,
                                                   int* __restrict__ totalsPad,
                                                   int e, int nbuk) {
    __shared__ int lh[MAXBUK];
    int t = threadIdx.x;
    lh[t] = 0;
    __syncthreads();
    int stride = gridDim.x * blockDim.x;
    for (int i = blockIdx.x * blockDim.x + t; i < e; i += stride) {
        int b = dst[i] >> BSH;
        if (b < 0) b = 0; if (b >= nbuk) b = nbuk - 1;
        atomicAdd(&lh[b], 1);
    }
    __syncthreads();
    if (t < nbuk && lh[t] > 0) atomicAdd(&totalsPad[t * PAD], lh[t]);
}

// Phase 2: exclusive scan of bucket totals (nbuk <= 256), emit bucket starts
// and init the padded reservation cursors.
__global__ __launch_bounds__(256) void bucket_scan(const int* __restrict__ totalsPad,
                                                   int* __restrict__ bs,
                                                   int* __restrict__ cursorPad,
                                                   int nbuk, int e) {
    __shared__ int buf[256];
    int t = threadIdx.x;
    int v = (t < nbuk) ? totalsPad[t * PAD] : 0;
    buf[t] = v;
    __syncthreads();
    #pragma unroll
    for (int off = 1; off < 256; off <<= 1) {
        int x = (t >= off) ? buf[t - off] : 0;
        __syncthreads();
        buf[t] += x;
        __syncthreads();
    }
    int excl = buf[t] - v;
    if (t < nbuk) {
        bs[t] = excl;
        cursorPad[t * PAD] = excl;
    }
    if (t == 0) bs[nbuk] = e;
}

// Phase 3: scatter (dst,src) pairs into bucket-major order. Each block owns a
// contiguous edge chunk; reserves per-bucket space once (padded atomics), then
// writes pairs into ~256B contiguous runs per (block,bucket) -> L2
// write-combining keeps HBM lines dense.
__global__ __launch_bounds__(256) void bucket_scatter(
    const int* __restrict__ src, const int* __restrict__ dst,
    int* __restrict__ cursorPad, u64* __restrict__ pairs,
    int e, int nbuk, int chunk) {
    __shared__ int lh[MAXBUK];
    __shared__ int lcur[MAXBUK];
    int t = threadIdx.x;
    int lo = blockIdx.x * chunk;
    int hi = lo + chunk; if (hi > e) hi = e;
    if (lo >= e) return;                 // uniform per block
    lh[t] = 0;
    __syncthreads();
    for (int i = lo + t; i < hi; i += 256) {
        int b = dst[i] >> BSH;
        if (b < 0) b = 0; if (b >= nbuk) b = nbuk - 1;
        atomicAdd(&lh[b], 1);
    }
    __syncthreads();
    if (t < nbuk) {
        int c = lh[t];
        lcur[t] = (c > 0) ? atomicAdd(&cursorPad[t * PAD], c) : 0;
    }
    __syncthreads();
    for (int i = lo + t; i < hi; i += 256) {
        int d = dst[i], s = src[i];
        int b = d >> BSH;
        if (b < 0) b = 0; if (b >= nbuk) b = nbuk - 1;
        int slot = atomicAdd(&lcur[b], 1);
        if (slot >= 0 && slot < e)
            pairs[slot] = (((u64)(unsigned)d) << 32) | (unsigned)(s);
    }
}

// Phase 4: per-bucket finalize. One block per bucket: LDS per-dst histogram,
// LDS scan, LDS-atomic ranking. No global atomics; srcperm stores confined to
// a ~32KB L2-hot window. Emits compact starts[] (deg = starts[d+1]-starts[d]).
__global__ __launch_bounds__(1024) void csr_finalize(
    const u64* __restrict__ pairs, const int* __restrict__ bs,
    int* __restrict__ starts, int* __restrict__ srcperm, int n, int e, int nbuk) {
    __shared__ int hist[NPB];
    __shared__ int excl[NPB];
    __shared__ int lcur[NPB];
    int b = blockIdx.x;
    int t = threadIdx.x;
    int d0 = b << BSH;
    int lo = bs[b], hi = bs[b + 1];
    for (int i = t; i < NPB; i += 1024) { hist[i] = 0; lcur[i] = 0; }
    __syncthreads();
    for (int i = lo + t; i < hi; i += 1024) {
        int ld = (int)(pairs[i] >> 32) - d0;
        if (ld < 0) ld = 0; if (ld >= NPB) ld = NPB - 1;
        atomicAdd(&hist[ld], 1);
    }
    __syncthreads();
    if (t < NPB) excl[t] = hist[t];
    __syncthreads();
    #pragma unroll
    for (int off = 1; off < NPB; off <<= 1) {
        int x = 0;
        if (t < NPB && t >= off) x = excl[t - off];
        __syncthreads();
        if (t < NPB) excl[t] += x;
        __syncthreads();
    }
    if (t < NPB) excl[t] -= hist[t];     // inclusive -> exclusive
    __syncthreads();
    if (t < NPB) {
        int d = d0 + t;
        if (d < n) starts[d] = lo + excl[t];
    }
    if (b == nbuk - 1 && t == 0) starts[n] = e;
    for (int i = lo + t; i < hi; i += 1024) {
        u64 p = pairs[i];
        int d  = (int)(p >> 32);
        int s  = (int)(p & 0xffffffffu);
        int ld = d - d0;
        if (ld < 0) ld = 0; if (ld >= NPB) ld = NPB - 1;
        int r = atomicAdd(&lcur[ld], 1);
        int slot = lo + excl[ld] + r;
        if (slot >= 0 && slot < e) srcperm[slot] = s;
    }
}

// ---------------------------------------------------------------------------
// One wave per dst node, two 32-lane halves over even/odd edges with
// independent online-softmax states (merged at end). Lane j owns dims
// {4j..4j+3}; head reduce via DPP quad_perm. One dwordx4 per lane fetches the
// interleaved {K,V} fragment. 2-deep pipeline.
// ---------------------------------------------------------------------------
__global__ __launch_bounds__(256) void attn_kernel(
    const u16* __restrict__ Qb, const uint4* __restrict__ KVb,
    const int* __restrict__ starts, const int* __restrict__ srcperm,
    float* __restrict__ out, int n, int e) {
    int node = blockIdx.x * 4 + (threadIdx.x >> 6);
    int lane = threadIdx.x & 63;
    if (node >= n) return;
    int j = lane & 31;      // dim group: dims 4j..4j+3
    int h = lane >> 5;      // half: processes edges with (idx & 1) == h

    uint2 qp = *(const uint2*)(Qb + (size_t)node * HIDDEN + j * 4);
    float q0 = lo16f(qp.x), q1 = hi16f(qp.x);
    float q2 = lo16f(qp.y), q3 = hi16f(qp.y);

    int off = starts[node];
    int deg = starts[node + 1] - off;
    if (deg < 0) deg = 0; if (deg > e) deg = e;
    if (off < 0) off = 0; if (off > e - deg) off = e - deg;

    float mrun = -1e30f, lrun = 0.f;
    float o0 = 0.f, o1 = 0.f, o2 = 0.f, o3 = 0.f;

    for (int base = 0; base < deg; base += 64) {
        int cnt = deg - base; if (cnt > 64) cnt = 64;
        int sv = 0;
        if (lane < cnt) {
            int s = srcperm[off + base + lane];
            if (s < 0) s = 0; if (s >= n) s = n - 1;
            sv = s;
        }
        uint4 kvA = KVb[(size_t)__shfl(sv, h) * 32 + j];
        uint4 kvB = KVb[(size_t)__shfl(sv, 2 + h) * 32 + j];
        for (int i = 0; i < cnt; i += 2) {
            uint4 kv = kvA;
            kvA = kvB;
            int ip = i + 4 + h; if (ip > 63) ip = 63;
            kvB = KVb[(size_t)__shfl(sv, ip) * 32 + j];

            float p = q0 * lo16f(kv.x) + q1 * hi16f(kv.x)
                    + q2 * lo16f(kv.y) + q3 * hi16f(kv.y);
            p += dpp_qperm<0xB1>(p);
            p += dpp_qperm<0x4E>(p);
            bool valid = (i + h) < cnt;
            float pv = valid ? p : -1e30f;
            float mn  = fmaxf(mrun, pv);
            float scl = __expf(mrun - mn);
            float w   = valid ? __expf(pv - mn) : 0.f;
            lrun = lrun * scl + w;
            o0 = o0 * scl + w * lo16f(kv.z);
            o1 = o1 * scl + w * hi16f(kv.z);
            o2 = o2 * scl + w * lo16f(kv.w);
            o3 = o3 * scl + w * hi16f(kv.w);
            mrun = mn;
        }
    }

    float mo  = __shfl_xor(mrun, 32);
    float lo_ = __shfl_xor(lrun, 32);
    float p0 = __shfl_xor(o0, 32), p1 = __shfl_xor(o1, 32);
    float p2 = __shfl_xor(o2, 32), p3 = __shfl_xor(o3, 32);
    float m2 = fmaxf(mrun, mo);
    float sa = __expf(mrun - m2), sb = __expf(mo - m2);
    float l  = lrun * sa + lo_ * sb;
    float inv = (l > 0.f) ? 1.f / l : 0.f;
    if (h == 0) {
        float4 r;
        r.x = (o0 * sa + p0 * sb) * inv;
        r.y = (o1 * sa + p1 * sb) * inv;
        r.z = (o2 * sa + p2 * sb) * inv;
        r.w = (o3 * sa + p3 * sb) * inv;
        *(float4*)(out + (size_t)node * HIDDEN + j * 4) = r;
    }
}

// ---------------------------------------------------------------------------
extern "C" void kernel_launch(void* const* d_in, const int* in_sizes, int n_in,
                              void* d_out, int out_size, void* d_ws, size_t ws_size,
                              hipStream_t stream) {
    const float* h   = (const float*)d_in[0];
    const int*   src = (const int*)d_in[1];
    const int*   dst = (const int*)d_in[2];
    const float* Wq  = (const float*)d_in[3];
    const float* bq  = (const float*)d_in[4];
    const float* Wk  = (const float*)d_in[5];
    const float* bk  = (const float*)d_in[6];
    const float* Wv  = (const float*)d_in[7];
    const float* bv  = (const float*)d_in[8];
    float* out = (float*)d_out;

    const int n = in_sizes[0] / HIDDEN;   // 100000
    const int e = in_sizes[1];            // 1600000
    const int nbuk = (n + NPB - 1) >> BSH; // 196 (<= MAXBUK required)

    // Workspace carve — ~83.9 MB (ws_size >= 84.5 MB proven).
    char* ws = (char*)d_ws;
    auto align256 = [](size_t x) { return (x + 255) & ~(size_t)255; };
    int* starts    = (int*)ws; ws += align256((size_t)(n + 1) * 4);
    int* bs        = (int*)ws; ws += align256((size_t)(MAXBUK + 1) * 4);
    int* totalsPad = (int*)ws; ws += align256((size_t)MAXBUK * PAD * 4);
    int* cursorPad = (int*)ws; ws += align256((size_t)MAXBUK * PAD * 4);
    int* srcperm   = (int*)ws; ws += align256((size_t)e * 4);
    u16* packed    = (u16*)ws; ws += align256((size_t)24 * 4 * 64 * 8 * sizeof(u16));
    u16* Qb        = (u16*)ws; ws += align256((size_t)n * HIDDEN * sizeof(u16));
    u16* KVb       = (u16*)ws; ws += align256((size_t)n * 256 * sizeof(u16));

    // pairs scratch in d_out (e*8 = 12.8MB <= 51.2MB); consumed by
    // csr_finalize before attn writes out.
    u64* pairs = (u64*)d_out;

    hipMemsetAsync(totalsPad, 0, (size_t)MAXBUK * PAD * 4, stream);

    pack_w_kernel<<<(24 * 4 * 64 * 8 + 255) / 256, 256, 0, stream>>>(Wq, Wk, Wv, packed);
    qkv_gemm_mfma<<<(n + 63) / 64, 256, 0, stream>>>(h, packed, bq, bk, bv, Qb, KVb, n);

    bucket_hist<<<256, 256, 0, stream>>>(dst, totalsPad, e, nbuk);
    bucket_scan<<<1, 256, 0, stream>>>(totalsPad, bs, cursorPad, nbuk, e);
    const int chunk = (e + 255) / 256;
    bucket_scatter<<<256, 256, 0, stream>>>(src, dst, cursorPad, pairs, e, nbuk, chunk);
    csr_finalize<<<nbuk, 1024, 0, stream>>>(pairs, bs, starts, srcperm, n, e, nbuk);

    attn_kernel<<<(n + 3) / 4, 256, 0, stream>>>(Qb, (const uint4*)KVb, starts, srcperm,
                                                 out, n, e);
}

// Round 4
// 327.254 us; speedup vs baseline: 1.6312x; 1.0127x over previous
//
#include <hip/hip_runtime.h>
#include <stdint.h>

typedef unsigned short u16;
typedef uint32_t u32;
typedef u16      u16x8 __attribute__((ext_vector_type(8)));
typedef _Float16 f16x8 __attribute__((ext_vector_type(8)));
typedef _Float16 f16x2 __attribute__((ext_vector_type(2)));
typedef float    f32x4 __attribute__((ext_vector_type(4)));
typedef unsigned long long u64;

#define HIDDEN 128   // NH(8) * HD(16)
#define BSH    9     // bucket shift: 512 nodes/bucket
#define NPB    (1 << BSH)
#define MAXBUK 256   // requires (n+NPB-1)>>BSH <= 256  (n=100000 -> 196)
#define PAD    16    // 64B stride for atomic counters

// INPUTS fp32, OUTPUT fp32. W/Q/K/V stored fp16 (absmax 0.031 vs 0.105
// threshold), all accumulation fp32.
//
// Round 3 resubmit (round-3 bench was an infra failure: container acquire
// failed twice; no kernel-fault evidence). Changes vs round 2:
//  - attn: v_dot2_f32_f16 for scores (Q kept packed half2), exp2-domain
//    softmax, ds_bpermute index broadcast replaced by direct same-address
//    srcperm loads pipelined 8 edges ahead (KV gather 4 ahead).
//  - CSR: pairs packed to u32 ((d&511)<<17 | src; bucket implied by position)
//    -> halves scatter write + finalize read traffic.

__device__ __forceinline__ float h2f(u16 u) {
    _Float16 h; __builtin_memcpy(&h, &u, 2); return (float)h;
}
__device__ __forceinline__ u16 f2h(float f) {
    _Float16 h = (_Float16)f; u16 u; __builtin_memcpy(&u, &h, 2); return u;
}
__device__ __forceinline__ f16x2 as_h2(uint32_t u) {
    return __builtin_bit_cast(f16x2, u);
}

// quad_perm DPP cross-lane: CTRL=0xB1 -> lane^1, CTRL=0x4E -> lane^2
template <int CTRL>
__device__ __forceinline__ float dpp_qperm(float x) {
#if __has_builtin(__builtin_amdgcn_update_dpp)
    int r = __builtin_amdgcn_update_dpp(0, __builtin_bit_cast(int, x), CTRL, 0xF, 0xF, true);
    return __builtin_bit_cast(float, r);
#else
    return __shfl_xor(x, (CTRL == 0xB1) ? 1 : 2);
#endif
}

__device__ __forceinline__ float fdot2(f16x2 a, f16x2 b, float c) {
#if __has_builtin(__builtin_amdgcn_fdot2)
    return __builtin_amdgcn_fdot2(a, b, c, false);
#else
    return c + (float)a.x * (float)b.x + (float)a.y * (float)b.y;
#endif
}

__device__ __forceinline__ float exp2f_fast(float x) {
#if __has_builtin(__builtin_amdgcn_exp2f)
    return __builtin_amdgcn_exp2f(x);
#else
    return __expf(x * 0.6931471805599453f);
#endif
}

// ---------------------------------------------------------------------------
// Pack [Wq|Wk|Wv] (128x128 row-major fp32 W[k][c]) into fp16 MFMA B-fragment
// order for mfma_f32_16x16x32_f16: lane l elem j holds
// B[k = kt*32 + (l>>4)*8 + j][c = (ct&7)*16 + (l&15)], ct = w*8 + col_tile.
// ---------------------------------------------------------------------------
__global__ void pack_w_kernel(const float* __restrict__ Wq, const float* __restrict__ Wk,
                              const float* __restrict__ Wv, u16* __restrict__ packed) {
    int tid = blockIdx.x * blockDim.x + threadIdx.x;
    if (tid >= 24 * 4 * 64 * 8) return;
    int j    = tid & 7;
    int lane = (tid >> 3) & 63;
    int kt   = (tid >> 9) & 3;
    int ct   = tid >> 11;            // 0..23
    int w    = ct >> 3;
    int k    = kt * 32 + ((lane >> 4) << 3) + j;
    int c    = (ct & 7) * 16 + (lane & 15);
    const float* W = (w == 0) ? Wq : (w == 1) ? Wk : Wv;
    packed[tid] = f2h(W[k * HIDDEN + c]);
}

// ---------------------------------------------------------------------------
// MFMA QKV projection. Block 256 = 4 waves; wave: 16 rows x 384 cols.
// Q row-major fp16; K/V interleaved for attn:
//   u16 index = node*256 + (cc>>2)*8 + (isV ? 4 : 0) + (cc&3)
// ---------------------------------------------------------------------------
__global__ __launch_bounds__(256) void qkv_gemm_mfma(
    const float* __restrict__ h, const u16* __restrict__ packed,
    const float* __restrict__ bq, const float* __restrict__ bk, const float* __restrict__ bv,
    u16* __restrict__ Qb, u16* __restrict__ KVb, int n) {
    int wave = threadIdx.x >> 6, lane = threadIdx.x & 63;
    int row0 = blockIdx.x * 64 + wave * 16;
    int m = lane & 15, quad = lane >> 4;
    int arow = row0 + m;

    u16x8 a[4];
    if (arow < n) {
        const float* hp = h + (size_t)arow * HIDDEN + quad * 8;
        #pragma unroll
        for (int kt = 0; kt < 4; ++kt) {
            f32x4 lo = *(const f32x4*)(hp + kt * 32);
            f32x4 hi = *(const f32x4*)(hp + kt * 32 + 4);
            #pragma unroll
            for (int j = 0; j < 4; ++j) {
                a[kt][j]     = f2h(lo[j]);
                a[kt][j + 4] = f2h(hi[j]);
            }
        }
    } else {
        #pragma unroll
        for (int kt = 0; kt < 4; ++kt) a[kt] = (u16x8){0,0,0,0,0,0,0,0};
    }

    #pragma unroll
    for (int ct = 0; ct < 24; ++ct) {
        f32x4 acc = {0.f, 0.f, 0.f, 0.f};
        #pragma unroll
        for (int kt = 0; kt < 4; ++kt) {
            u16x8 b = *(const u16x8*)(packed + (((ct * 4 + kt) * 64 + lane) << 3));
            acc = __builtin_amdgcn_mfma_f32_16x16x32_f16(
                __builtin_bit_cast(f16x8, a[kt]), __builtin_bit_cast(f16x8, b),
                acc, 0, 0, 0);
        }
        int w  = ct >> 3;                 // compile-time after unroll
        int cc = (ct & 7) * 16 + m;
        const float* bp = (w == 0) ? bq : (w == 1) ? bk : bv;
        float bias = bp[cc];
        #pragma unroll
        for (int r = 0; r < 4; ++r) {
            int rr = row0 + quad * 4 + r;
            if (rr < n) {
                u16 val = f2h(acc[r] + bias);
                if (w == 0) {
                    Qb[(size_t)rr * HIDDEN + cc] = val;
                } else {
                    KVb[(size_t)rr * 256 + ((cc >> 2) << 3) + ((w == 2) ? 4 : 0) + (cc & 3)] = val;
                }
            }
        }
    }
}

// ---------------------------------------------------------------------------
// CSR build, two-level counting sort.
// ---------------------------------------------------------------------------
__global__ __launch_bounds__(256) void bucket_hist(const int* __restrict__ dst,
                                                   int* __restrict__ totalsPad,
                                                   int e, int nbuk) {
    __shared__ int lh[MAXBUK];
    int t = threadIdx.x;
    lh[t] = 0;
    __syncthreads();
    int stride = gridDim.x * blockDim.x;
    for (int i = blockIdx.x * blockDim.x + t; i < e; i += stride) {
        int b = dst[i] >> BSH;
        if (b < 0) b = 0; if (b >= nbuk) b = nbuk - 1;
        atomicAdd(&lh[b], 1);
    }
    __syncthreads();
    if (t < nbuk && lh[t] > 0) atomicAdd(&totalsPad[t * PAD], lh[t]);
}

__global__ __launch_bounds__(256) void bucket_scan(const int* __restrict__ totalsPad,
                                                   int* __restrict__ bs,
                                                   int* __restrict__ cursorPad,
                                                   int nbuk, int e) {
    __shared__ int buf[256];
    int t = threadIdx.x;
    int v = (t < nbuk) ? totalsPad[t * PAD] : 0;
    buf[t] = v;
    __syncthreads();
    #pragma unroll
    for (int off = 1; off < 256; off <<= 1) {
        int x = (t >= off) ? buf[t - off] : 0;
        __syncthreads();
        buf[t] += x;
        __syncthreads();
    }
    int excl = buf[t] - v;
    if (t < nbuk) {
        bs[t] = excl;
        cursorPad[t * PAD] = excl;
    }
    if (t == 0) bs[nbuk] = e;
}

// Pairs packed u32: ((d & 511) << 17) | (src & 0x1FFFF). Bucket implied by
// position (bucket-major order); n < 131072 so 17 bits suffice for src.
__global__ __launch_bounds__(256) void bucket_scatter(
    const int* __restrict__ src, const int* __restrict__ dst,
    int* __restrict__ cursorPad, u32* __restrict__ pairs,
    int e, int nbuk, int chunk) {
    __shared__ int lh[MAXBUK];
    __shared__ int lcur[MAXBUK];
    int t = threadIdx.x;
    int lo = blockIdx.x * chunk;
    int hi = lo + chunk; if (hi > e) hi = e;
    if (lo >= e) return;                 // uniform per block (lo is block-uniform)
    lh[t] = 0;
    __syncthreads();
    for (int i = lo + t; i < hi; i += 256) {
        int b = dst[i] >> BSH;
        if (b < 0) b = 0; if (b >= nbuk) b = nbuk - 1;
        atomicAdd(&lh[b], 1);
    }
    __syncthreads();
    if (t < nbuk) {
        int c = lh[t];
        lcur[t] = (c > 0) ? atomicAdd(&cursorPad[t * PAD], c) : 0;
    }
    __syncthreads();
    for (int i = lo + t; i < hi; i += 256) {
        int d = dst[i], s = src[i];
        int b = d >> BSH;
        if (b < 0) b = 0; if (b >= nbuk) b = nbuk - 1;
        int slot = atomicAdd(&lcur[b], 1);
        if (slot >= 0 && slot < e)
            pairs[slot] = (((u32)d & (NPB - 1)) << 17) | ((u32)s & 0x1FFFF);
    }
}

// Phase 4: per-bucket finalize. One block per bucket: LDS per-dst histogram,
// LDS scan, LDS-atomic ranking. Emits compact starts[] (deg from diff).
__global__ __launch_bounds__(1024) void csr_finalize(
    const u32* __restrict__ pairs, const int* __restrict__ bs,
    int* __restrict__ starts, int* __restrict__ srcperm, int n, int e, int nbuk) {
    __shared__ int hist[NPB];
    __shared__ int excl[NPB];
    __shared__ int lcur[NPB];
    int b = blockIdx.x;
    int t = threadIdx.x;
    int d0 = b << BSH;
    int lo = bs[b], hi = bs[b + 1];
    for (int i = t; i < NPB; i += 1024) { hist[i] = 0; lcur[i] = 0; }
    __syncthreads();
    for (int i = lo + t; i < hi; i += 1024) {
        int ld = (int)(pairs[i] >> 17);          // 9 bits by construction
        atomicAdd(&hist[ld], 1);
    }
    __syncthreads();
    if (t < NPB) excl[t] = hist[t];
    __syncthreads();
    #pragma unroll
    for (int off = 1; off < NPB; off <<= 1) {
        int x = 0;
        if (t < NPB && t >= off) x = excl[t - off];
        __syncthreads();
        if (t < NPB) excl[t] += x;
        __syncthreads();
    }
    if (t < NPB) excl[t] -= hist[t];     // inclusive -> exclusive
    __syncthreads();
    if (t < NPB) {
        int d = d0 + t;
        if (d < n) starts[d] = lo + excl[t];
    }
    if (b == nbuk - 1 && t == 0) starts[n] = e;
    for (int i = lo + t; i < hi; i += 1024) {
        u32 p = pairs[i];
        int ld = (int)(p >> 17);
        int s  = (int)(p & 0x1FFFF);
        int r = atomicAdd(&lcur[ld], 1);
        int slot = lo + excl[ld] + r;
        if (slot >= 0 && slot < e) srcperm[slot] = s;
    }
}

// ---------------------------------------------------------------------------
// One wave per dst node, two 32-lane halves over even/odd edges with
// independent online-softmax states (merged at end). Lane j owns dims
// {4j..4j+3}; head reduce via DPP quad_perm; scores via v_dot2_f32_f16;
// exp2-domain softmax. Index loads (same-address broadcast per half) pipelined
// 8 edges ahead; KV dwordx4 gather 4 edges ahead.
// ---------------------------------------------------------------------------
__global__ __launch_bounds__(256) void attn_kernel(
    const u16* __restrict__ Qb, const uint4* __restrict__ KVb,
    const int* __restrict__ starts, const int* __restrict__ srcperm,
    float* __restrict__ out, int n, int e) {
    int node = blockIdx.x * 4 + (threadIdx.x >> 6);
    int lane = threadIdx.x & 63;
    if (node >= n) return;
    int j = lane & 31;      // dim group: dims 4j..4j+3
    int h = lane >> 5;      // half: processes edges with (idx & 1) == h

    uint2 qp = *(const uint2*)(Qb + (size_t)node * HIDDEN + j * 4);
    f16x2 q01 = as_h2(qp.x), q23 = as_h2(qp.y);

    int off = starts[node];
    int deg = starts[node + 1] - off;
    if (deg < 0) deg = 0; if (deg > e) deg = e;
    if (off < 0) off = 0; if (off > e - deg) off = e - deg;

    const float LOG2E = 1.44269504f;
    float mrun = -1e30f, lrun = 0.f;
    float o0 = 0.f, o1 = 0.f, o2 = 0.f, o3 = 0.f;

    if (deg > 0) {
        const int last = deg - 1;
        const int* sp = srcperm + off;
        // clamped index load (same address across the 32-lane half -> broadcast)
        #define IDX(ii) (sp[((ii) > last) ? last : (ii)])
        // clamped KV row fetch
        #define KVL(s)  (KVb[(size_t)(((unsigned)(s) < (unsigned)n) ? (unsigned)(s) : 0u) * 32 + j])

        int sA = IDX(h);
        int sB = IDX(h + 2);
        int sC = IDX(h + 4);
        int sD = IDX(h + 6);
        uint4 kvA = KVL(sA);
        uint4 kvB = KVL(sB);

        for (int i = 0; i < deg; i += 2) {
            uint4 kv = kvA;
            kvA = kvB;
            kvB = KVL(sC);                  // prefetch edge i+4+h
            sC = sD;
            sD = IDX(i + 8 + h);            // prefetch index for edge i+8+h

            float p = fdot2(as_h2(kv.x), q01, fdot2(as_h2(kv.y), q23, 0.f));
            p += dpp_qperm<0xB1>(p);        // lane^1
            p += dpp_qperm<0x4E>(p);        // lane^2 -> head sum in all 4
            p *= LOG2E;                     // exp2 domain
            bool valid = (i + h) < deg;
            float pv = valid ? p : -1e30f;
            float mn  = fmaxf(mrun, pv);
            float scl = exp2f_fast(mrun - mn);
            float w   = valid ? exp2f_fast(pv - mn) : 0.f;
            lrun = lrun * scl + w;
            f16x2 vz = as_h2(kv.z), vw = as_h2(kv.w);
            o0 = o0 * scl + w * (float)vz.x;
            o1 = o1 * scl + w * (float)vz.y;
            o2 = o2 * scl + w * (float)vw.x;
            o3 = o3 * scl + w * (float)vw.y;
            mrun = mn;
        }
        #undef IDX
        #undef KVL
    }

    // merge the two half-wave states
    float mo  = __shfl_xor(mrun, 32);
    float lo_ = __shfl_xor(lrun, 32);
    float p0 = __shfl_xor(o0, 32), p1 = __shfl_xor(o1, 32);
    float p2 = __shfl_xor(o2, 32), p3 = __shfl_xor(o3, 32);
    float m2 = fmaxf(mrun, mo);
    float sa = exp2f_fast(mrun - m2), sb = exp2f_fast(mo - m2);
    float l  = lrun * sa + lo_ * sb;
    float inv = (l > 0.f) ? 1.f / l : 0.f;
    if (h == 0) {
        float4 r;
        r.x = (o0 * sa + p0 * sb) * inv;
        r.y = (o1 * sa + p1 * sb) * inv;
        r.z = (o2 * sa + p2 * sb) * inv;
        r.w = (o3 * sa + p3 * sb) * inv;
        *(float4*)(out + (size_t)node * HIDDEN + j * 4) = r;
    }
}

// ---------------------------------------------------------------------------
extern "C" void kernel_launch(void* const* d_in, const int* in_sizes, int n_in,
                              void* d_out, int out_size, void* d_ws, size_t ws_size,
                              hipStream_t stream) {
    const float* h   = (const float*)d_in[0];
    const int*   src = (const int*)d_in[1];
    const int*   dst = (const int*)d_in[2];
    const float* Wq  = (const float*)d_in[3];
    const float* bq  = (const float*)d_in[4];
    const float* Wk  = (const float*)d_in[5];
    const float* bk  = (const float*)d_in[6];
    const float* Wv  = (const float*)d_in[7];
    const float* bv  = (const float*)d_in[8];
    float* out = (float*)d_out;

    const int n = in_sizes[0] / HIDDEN;   // 100000
    const int e = in_sizes[1];            // 1600000
    const int nbuk = (n + NPB - 1) >> BSH; // 196 (<= MAXBUK required)

    // Workspace carve — ~83.9 MB (ws_size >= 84.5 MB proven).
    char* ws = (char*)d_ws;
    auto align256 = [](size_t x) { return (x + 255) & ~(size_t)255; };
    int* starts    = (int*)ws; ws += align256((size_t)(n + 1) * 4);
    int* bs        = (int*)ws; ws += align256((size_t)(MAXBUK + 1) * 4);
    int* totalsPad = (int*)ws; ws += align256((size_t)MAXBUK * PAD * 4);
    int* cursorPad = (int*)ws; ws += align256((size_t)MAXBUK * PAD * 4);
    int* srcperm   = (int*)ws; ws += align256((size_t)e * 4);
    u16* packed    = (u16*)ws; ws += align256((size_t)24 * 4 * 64 * 8 * sizeof(u16));
    u16* Qb        = (u16*)ws; ws += align256((size_t)n * HIDDEN * sizeof(u16));
    u16* KVb       = (u16*)ws; ws += align256((size_t)n * 256 * sizeof(u16));

    // pairs scratch in d_out (e*4 = 6.4MB <= 51.2MB); consumed by
    // csr_finalize before attn writes out.
    u32* pairs = (u32*)d_out;

    hipMemsetAsync(totalsPad, 0, (size_t)MAXBUK * PAD * 4, stream);

    pack_w_kernel<<<(24 * 4 * 64 * 8 + 255) / 256, 256, 0, stream>>>(Wq, Wk, Wv, packed);
    qkv_gemm_mfma<<<(n + 63) / 64, 256, 0, stream>>>(h, packed, bq, bk, bv, Qb, KVb, n);

    bucket_hist<<<256, 256, 0, stream>>>(dst, totalsPad, e, nbuk);
    bucket_scan<<<1, 256, 0, stream>>>(totalsPad, bs, cursorPad, nbuk, e);
    const int chunk = (e + 255) / 256;
    bucket_scatter<<<256, 256, 0, stream>>>(src, dst, cursorPad, pairs, e, nbuk, chunk);
    csr_finalize<<<nbuk, 1024, 0, stream>>>(pairs, bs, starts, srcperm, n, e, nbuk);

    attn_kernel<<<(n + 3) / 4, 256, 0, stream>>>(Qb, (const uint4*)KVb, starts, srcperm,
                                                 out, n, e);
}